// Round 10
// baseline (277.320 us; speedup 1.0000x reference)
//
#include <hip/hip_runtime.h>
#include <math.h>

namespace {

constexpr int kB = 4, kN = 512, kC = 256, kH = 8, kDG = 6, kHID = 16;

constexpr int S_BT = 20;    // bias row stride (floats)
constexpr int S_AT = 516;   // kernel-B sAtt row stride
constexpr int S_G  = 10;    // sG per-pair stride (uints): lanes p hit distinct banks
constexpr int S_L  = 18;    // sL (n,h)-row stride (floats): 2-way max on QK b64 writes

typedef _Float16 half2v __attribute__((ext_vector_type(2)));
typedef _Float16 half4v __attribute__((ext_vector_type(4)));
typedef float float4v __attribute__((ext_vector_type(4)));
typedef float float2v __attribute__((ext_vector_type(2)));
typedef unsigned uint2v __attribute__((ext_vector_type(2)));

__device__ __forceinline__ float swishf(float x) {
    return x * __builtin_amdgcn_rcpf(1.0f + __expf(-x));
}

__device__ __forceinline__ unsigned pk16(float a, float b) {
    unsigned short ha = __builtin_bit_cast(unsigned short, (_Float16)a);
    unsigned short hb = __builtin_bit_cast(unsigned short, (_Float16)b);
    return (unsigned)ha | ((unsigned)hb << 16);
}

__device__ __forceinline__ unsigned pkrtz(float a, float b) {
    return __builtin_bit_cast(unsigned, __builtin_amdgcn_cvt_pkrtz(a, b));
}

__device__ __forceinline__ float4v mfma16(half4v a, half4v b, float4v c) {
    return __builtin_amdgcn_mfma_f32_16x16x16f16(a, b, c, 0, 0, 0);
}

// QKV projection (col-split 128) + mask decode/compaction (block 512).
__global__ __launch_bounds__(256) void k_qkvc(
    const float* __restrict__ x,
    const float* __restrict__ wq, const float* __restrict__ bq,
    const float* __restrict__ wk, const float* __restrict__ bk,
    const float* __restrict__ wv, const float* __restrict__ bv,
    unsigned* __restrict__ Qh, unsigned* __restrict__ Kh,
    unsigned* __restrict__ Vh,
    const unsigned char* __restrict__ mraw,
    int* __restrict__ list, int* __restrict__ meta) {
    const int t = threadIdx.x;

    if (blockIdx.x == 512) {
        __shared__ int s_isbool;
        if (t == 0) s_isbool = 0;
        __syncthreads();
        int found = 0;
        for (int i = t; i < kB * kN; i += 256)
            if ((i & 3) && mraw[i]) found = 1;
        if (found) atomicOr(&s_isbool, 1);
        __syncthreads();
        const int isb = s_isbool;
        const int b = t >> 6, lane = t & 63;
        const int* mi = (const int*)mraw;
        int base = 0;
        for (int c = 0; c < 8; ++c) {
            const int m = c * 64 + lane;
            const int idx = b * kN + m;
            const int valid = isb ? (mraw[idx] != 0) : (mi[idx] != 0);
            unsigned long long bal = __ballot(valid);
            int rank = (int)__popcll(bal & ((1ull << lane) - 1ull));
            if (valid) list[b * kN + base + rank] = m;
            base += (int)__popcll(bal);
        }
        for (int i = base + lane; i < kN; i += 64)
            list[b * kN + i] = (base == 0) ? i : 0;
        if (lane == 0) {
            meta[b] = (base == 0) ? kN : base;
            meta[4 + b] = (base == 0);
        }
        return;
    }

    __shared__ float sx[8][kC];
    const int r0 = (blockIdx.x >> 1) * 8;
    const int c0 = (blockIdx.x & 1) * 128;
    const int col = t & 127;
    const int g = t >> 7;
    #pragma unroll
    for (int r = 0; r < 8; ++r) sx[r][t] = x[(r0 + r) * kC + t];
    __syncthreads();
    float aq[4] = {}, ak[4] = {}, av[4] = {};
    #pragma unroll 4
    for (int k = 0; k < kC; ++k) {
        const float q = wq[k * kC + c0 + col];
        const float kk = wk[k * kC + c0 + col];
        const float v = wv[k * kC + c0 + col];
        #pragma unroll
        for (int r = 0; r < 4; ++r) {
            const float xs = sx[g * 4 + r][k];
            aq[r] += xs * q;
            ak[r] += xs * kk;
            av[r] += xs * v;
        }
    }
    const float qb = bq[c0 + col], kb = bk[c0 + col], vb = bv[c0 + col];
    #pragma unroll
    for (int r = 0; r < 4; ++r) {
        const int row = r0 + g * 4 + r;
        const float qv = aq[r] + qb;
        const float kv = ak[r] + kb;
        const float vv = av[r] + vb;
        const float qn = __shfl_down(qv, 1);
        const float kn = __shfl_down(kv, 1);
        const float vn = __shfl_down(vv, 1);
        if ((t & 1) == 0) {
            const int ci = (c0 + col) >> 1;
            Qh[row * (kC / 2) + ci] = pk16(qv, qn);
            Kh[row * (kC / 2) + ci] = pk16(kv, kn);
            Vh[row * (kC / 2) + ci] = pk16(vv, vn);
        }
    }
}

// Kernel A: pre-softmax logits A_pre[b][n][h][m-compact] (f16) for a
// 16n x 16m tile, all 8 heads. Grid b(4) x mtile(32) x ntile(32); blocks
// with mtile*16 >= nv exit. Phases: stage -> QK GEMM (2 mfma/head/block)
// -> barrier -> MLP (one bg ds_read feeds 8 unrolled head-chains = 8-way
// ILP, no loads in chain) -> barrier -> coalesced f16 writeout.
__global__ __launch_bounds__(256, 4) void k_logits(
    const float* __restrict__ G,
    const unsigned* __restrict__ Qh,
    const unsigned* __restrict__ Kh,
    const float* __restrict__ w1, const float* __restrict__ b1,
    const float* __restrict__ w2, const float* __restrict__ b2,
    const float* __restrict__ w3, const float* __restrict__ b3,
    const int* __restrict__ list, const int* __restrict__ meta,
    unsigned* __restrict__ Ap) {
    __shared__ __align__(16) unsigned sG[256 * S_G];   // 10 KB packed f16 g
    __shared__ __align__(16) float sL[128 * S_L];      // 9 KB logits f32
    __shared__ __align__(16) float sB1T[kH * S_BT];
    __shared__ __align__(16) float sB2T[kH * S_BT];
    __shared__ __align__(16) float sW3T[kH * S_BT];
    __shared__ float sB3[kH];

    const int bid = blockIdx.x;
    const int b = bid >> 10;
    const int rem = bid & 1023;
    const int mtile = rem >> 5;
    const int ntile = rem & 31;
    const int nv = meta[b];
    if (mtile * 16 >= nv) return;
    const int allm = meta[4 + b];
    const int n0 = ntile * 16;
    const int m0c = mtile * 16;

    const int t = threadIdx.x;
    const int l = t & 63;
    const int p = l & 15;
    const int s = l >> 4;
    const int wid = t >> 6;

    // A-fragments: W1^T, W2^T (r6-verified layout: A row=l%16, k=4s+r)
    half4v a1f[kH], a2f[kH];
    #pragma unroll
    for (int h = 0; h < kH; ++h) {
        #pragma unroll
        for (int r = 0; r < 4; ++r) {
            const int k = 4 * s + r;
            a1f[h][r] = (k < kDG) ? (_Float16)w1[(h * kDG + k) * kHID + p]
                                  : (_Float16)0.f;
            a2f[h][r] = (_Float16)w2[(h * kHID + k) * kHID + p];
        }
    }
    if (t < 128) {
        const int hh = t >> 4, j = t & 15;
        sB1T[hh * S_BT + j] = b1[hh * kHID + j];
        sB2T[hh * S_BT + j] = b2[hh * kHID + j];
        sW3T[hh * S_BT + j] = w3[hh * kHID + j];
        if (j == 0) sB3[hh] = b3[hh];
    }
    // G staging: thread t -> pair (n = t>>4, mi = t&15)
    {
        const int m = list[b * kN + m0c + (t & 15)];
        const int n = n0 + (t >> 4);
        const float* gp = G + ((size_t)(b * kN + n) * kN + m) * kDG;
        unsigned* d = &sG[t * S_G];
        d[0] = pkrtz(gp[0], gp[1]);
        d[1] = pkrtz(gp[2], gp[3]);
        d[2] = pkrtz(gp[4], gp[5]);
        d[3] = 0; d[4] = 0; d[5] = 0; d[6] = 0; d[7] = 0;
    }
    __syncthreads();

    // QK GEMM: wave w -> heads 2w, 2w+1. A = K rows (m), B = Q rows (n).
    // C lane (p,s): col n=p, rows m-compact 4s+r. Writes afeat/16 to sL.
    {
        const int m = list[b * kN + m0c + p];
        const unsigned* krow = Kh + (size_t)(b * kN + m) * (kC / 2);
        const unsigned* qrow = Qh + (size_t)(b * kN + n0 + p) * (kC / 2);
        #pragma unroll
        for (int hh = 0; hh < 2; ++hh) {
            const int h = wid * 2 + hh;
            const uint2v k0 = *(const uint2v*)&krow[h * 16 + 2 * s];
            const uint2v q0 = *(const uint2v*)&qrow[h * 16 + 2 * s];
            const uint2v k1 = *(const uint2v*)&krow[h * 16 + 8 + 2 * s];
            const uint2v q1 = *(const uint2v*)&qrow[h * 16 + 8 + 2 * s];
            float4v c = {0.f, 0.f, 0.f, 0.f};
            c = mfma16(__builtin_bit_cast(half4v, k0),
                       __builtin_bit_cast(half4v, q0), c);
            c = mfma16(__builtin_bit_cast(half4v, k1),
                       __builtin_bit_cast(half4v, q1), c);
            const int base = (p * kH + h) * S_L + 4 * s;
            float2v lo = {c[0] * 0.0625f, c[1] * 0.0625f};
            float2v hi = {c[2] * 0.0625f, c[3] * 0.0625f};
            *(float2v*)&sL[base] = lo;
            *(float2v*)&sL[base + 2] = hi;
        }
    }
    __syncthreads();

    // MLP: wave w -> n-locals 4w..4w+3. One bg read feeds 8 head-chains.
    #pragma unroll 1
    for (int ni = 0; ni < 4; ++ni) {
        const int nl = wid * 4 + ni;
        const uint2v gu = *(const uint2v*)&sG[(nl * 16 + p) * S_G + 2 * s];
        const half4v bg = __builtin_bit_cast(half4v, gu);
        #pragma unroll
        for (int h = 0; h < kH; ++h) {
            const float4v bv1 = *(const float4v*)&sB1T[h * S_BT + s * 4];
            const float4v bv2 = *(const float4v*)&sB2T[h * S_BT + s * 4];
            const float4v w3f = *(const float4v*)&sW3T[h * S_BT + s * 4];
            half4v w3h;
            #pragma unroll
            for (int r = 0; r < 4; ++r) w3h[r] = (_Float16)w3f[r];
            const float b3s = sB3[h];
            const float4v b3v = {b3s, b3s, b3s, b3s};
            const float4v c1 = mfma16(a1f[h], bg, bv1);
            const uint2v x1u = {pkrtz(swishf(c1[0]), swishf(c1[1])),
                                pkrtz(swishf(c1[2]), swishf(c1[3]))};
            const float4v c2 = mfma16(a2f[h], __builtin_bit_cast(half4v, x1u), bv2);
            const uint2v x2u = {pkrtz(swishf(c2[0]), swishf(c2[1])),
                                pkrtz(swishf(c2[2]), swishf(c2[3]))};
            const float4v c3 = mfma16(w3h, __builtin_bit_cast(half4v, x2u), b3v);
            if (s == 0) {
                const int idx = (nl * kH + h) * S_L + p;
                sL[idx] = allm ? 0.f : (swishf(c3[0]) + sL[idx]);
            }
        }
    }
    __syncthreads();

    // Writeout: thread t -> (row = t>>1 of 128 (n,h)-rows, half = t&1)
    {
        const int row = t >> 1, half = t & 1;
        const int nl = row >> 3, h = row & 7;
        const float* src = &sL[row * S_L + half * 8];
        uint4 w;
        w.x = pkrtz(src[0], src[1]);
        w.y = pkrtz(src[2], src[3]);
        w.z = pkrtz(src[4], src[5]);
        w.w = pkrtz(src[6], src[7]);
        unsigned* dst = Ap + ((size_t)(b * kN + n0 + nl) * kH + h) * (kN / 2)
                        + mtile * 8 + half * 4;
        *(uint4*)dst = w;
    }
}

// Kernel B: softmax + att@V per (b,n). Logits read coalesced from A_pre.
__global__ __launch_bounds__(256, 8) void k_soft(
    const unsigned* __restrict__ Ap,
    const unsigned* __restrict__ Vh,
    const int* __restrict__ list, const int* __restrict__ meta,
    float* __restrict__ out) {
    __shared__ float sAtt[kH * S_AT];
    __shared__ int sList[kN];
    __shared__ float sInv[kH];

    const int bn = blockIdx.x;
    const int b = bn >> 9;
    const int t = threadIdx.x;
    const int nv = meta[b];

    sList[t] = list[b * kN + t];
    sList[t + 256] = list[b * kN + t + 256];
    const unsigned* arow = Ap + (size_t)bn * kH * (kN / 2);
    #pragma unroll
    for (int rep = 0; rep < 8; ++rep) {
        const unsigned val = arow[rep * 256 + t];   // h = rep, u = t
        const half2v hv = __builtin_bit_cast(half2v, val);
        float2v f = {(float)hv[0], (float)hv[1]};
        *(float2v*)&sAtt[rep * S_AT + 2 * t] = f;
    }
    __syncthreads();

    {
        const int hg = t >> 5;
        const int lane = t & 31;
        float mx = -3.4e38f;
        for (int idx = lane; idx < nv; idx += 32)
            mx = fmaxf(mx, sAtt[hg * S_AT + idx]);
        #pragma unroll
        for (int off = 16; off; off >>= 1)
            mx = fmaxf(mx, __shfl_xor(mx, off));
        float ls = 0.f;
        for (int idx = lane; idx < nv; idx += 32) {
            const float e = __expf(sAtt[hg * S_AT + idx] - mx);
            sAtt[hg * S_AT + idx] = e;
            ls += e;
        }
        #pragma unroll
        for (int off = 16; off; off >>= 1)
            ls += __shfl_xor(ls, off);
        if (lane == 0) sInv[hg] = 1.0f / ls;
    }
    __syncthreads();

    {
        const int hg = t >> 5;
        const int dp = (t >> 1) & 15;
        const int par = t & 1;
        const unsigned* vbp = Vh + (size_t)(b * kN) * (kC / 2) + hg * 16 + dp;
        float alo = 0.f, ahi = 0.f, blo = 0.f, bhi = 0.f;
        int mc = par;
        for (; mc + 2 < nv; mc += 4) {
            const float aw0 = sAtt[hg * S_AT + mc];
            const float aw1 = sAtt[hg * S_AT + mc + 2];
            const half2v v0 = __builtin_bit_cast(half2v, vbp[(size_t)sList[mc] * (kC / 2)]);
            const half2v v1 = __builtin_bit_cast(half2v, vbp[(size_t)sList[mc + 2] * (kC / 2)]);
            alo += aw0 * (float)v0[0];
            ahi += aw0 * (float)v0[1];
            blo += aw1 * (float)v1[0];
            bhi += aw1 * (float)v1[1];
        }
        for (; mc < nv; mc += 2) {
            const float aw = sAtt[hg * S_AT + mc];
            const half2v vv = __builtin_bit_cast(half2v, vbp[(size_t)sList[mc] * (kC / 2)]);
            alo += aw * (float)vv[0];
            ahi += aw * (float)vv[1];
        }
        alo += blo; ahi += bhi;
        alo += __shfl_xor(alo, 1);
        ahi += __shfl_xor(ahi, 1);
        out[bn * kC + t] = (par ? ahi : alo) * sInv[hg];
    }
}

// Final projection (col-split 128).
__global__ __launch_bounds__(256) void k_proj(
    const float* __restrict__ x,
    const float* __restrict__ w, const float* __restrict__ bias,
    float* __restrict__ y) {
    __shared__ float sx[8][kC];
    const int t = threadIdx.x;
    const int r0 = (blockIdx.x >> 1) * 8;
    const int c0 = (blockIdx.x & 1) * 128;
    const int col = t & 127;
    const int g = t >> 7;
    #pragma unroll
    for (int r = 0; r < 8; ++r) sx[r][t] = x[(r0 + r) * kC + t];
    __syncthreads();
    float acc[4] = {};
    #pragma unroll 4
    for (int k = 0; k < kC; ++k) {
        const float wv = w[k * kC + c0 + col];
        #pragma unroll
        for (int r = 0; r < 4; ++r) acc[r] += sx[g * 4 + r][k] * wv;
    }
    const float bb = bias[c0 + col];
    #pragma unroll
    for (int r = 0; r < 4; ++r)
        y[(r0 + g * 4 + r) * kC + c0 + col] = acc[r] + bb;
}

}  // namespace

extern "C" void kernel_launch(void* const* d_in, const int* in_sizes, int n_in,
                              void* d_out, int out_size, void* d_ws, size_t ws_size,
                              hipStream_t stream) {
    (void)in_sizes; (void)n_in; (void)out_size; (void)ws_size;
    const float* G  = (const float*)d_in[0];
    const float* cf = (const float*)d_in[1];
    const float* wq = (const float*)d_in[2];
    const float* bq = (const float*)d_in[3];
    const float* wk = (const float*)d_in[4];
    const float* bk = (const float*)d_in[5];
    const float* wv = (const float*)d_in[6];   // in_w
    const float* bv = (const float*)d_in[7];   // in_b
    const float* wo = (const float*)d_in[8];   // out_w
    const float* bo = (const float*)d_in[9];   // out_b
    const float* w1 = (const float*)d_in[10];
    const float* b1 = (const float*)d_in[11];
    const float* w2 = (const float*)d_in[12];
    const float* b2 = (const float*)d_in[13];
    const float* w3 = (const float*)d_in[14];
    const float* b3 = (const float*)d_in[15];
    const unsigned char* mraw = (const unsigned char*)d_in[16];

    const int rows = kB * kN;  // 2048
    unsigned* Qh = (unsigned*)d_ws;                       // 1 MB
    unsigned* Kh = Qh + (size_t)rows * (kC / 2);          // 1 MB
    unsigned* Vh = Kh + (size_t)rows * (kC / 2);          // 1 MB
    float* O = (float*)(Vh + (size_t)rows * (kC / 2));    // 2 MB
    unsigned* Ap = (unsigned*)(O + (size_t)rows * kC);    // 16.78 MB
    int* list = (int*)(Ap + (size_t)rows * kH * (kN / 2));
    int* meta = list + rows;

    k_qkvc<<<513, 256, 0, stream>>>(cf, wq, bq, wk, bk, wv, bv,
                                    Qh, Kh, Vh, mraw, list, meta);
    k_logits<<<4096, 256, 0, stream>>>(G, Qh, Kh, w1, b1, w2, b2, w3, b3,
                                       list, meta, Ap);
    k_soft<<<rows, 256, 0, stream>>>(Ap, Vh, list, meta, O);
    k_proj<<<512, 256, 0, stream>>>(O, wo, bo, (float*)d_out);
}